// Round 2
// baseline (373.438 us; speedup 1.0000x reference)
//
#include <hip/hip_runtime.h>

#define T_LEN 2048
#define BSZ   2
#define EMB   1280
#define NH    20
#define HD    64
#define NBH   (BSZ*NH)      // 40
#define NR    (T_LEN*BSZ)   // 4096
// HEAD_DIM^-0.5 * (1/ln2): scores computed in log2 domain -> raw v_exp_f32.
// exp2(s/ln2) == exp(s) exactly; Linv/meanw use the same convention.
#define QSCALE (0.125f * 1.4426950408889634f)

typedef short bf16x8 __attribute__((ext_vector_type(8)));
typedef short bf16x4 __attribute__((ext_vector_type(4)));
typedef float f32x4  __attribute__((ext_vector_type(4)));

__device__ inline short f2bf(float f) {
    union { float f; unsigned u; } v; v.f = f;
    unsigned u = v.u + 0x7FFF + ((v.u >> 16) & 1);
    return (short)(u >> 16);
}

// packed f32->bf16 convert (RNE), no builtin on gfx950 -> inline asm (T12)
__device__ inline unsigned cvt_pk_bf16(float lo, float hi) {
    unsigned r;
    asm("v_cvt_pk_bf16_f32 %0, %1, %2" : "=v"(r) : "v"(lo), "v"(hi));
    return r;
}

// async global->LDS, 16B per lane. LDS dest: wave-uniform base + lane*16.
__device__ inline void glds16(const short* g, short* l) {
    __builtin_amdgcn_global_load_lds(
        (const __attribute__((address_space(1))) void*)g,
        (__attribute__((address_space(3))) void*)l,
        16, 0, 0);
}

// ---------------- K0a: convert X -> bf16 ----------------
__global__ __launch_bounds__(256) void k_cvt_x(
    const float* __restrict__ X, short* __restrict__ Xb)
{
    size_t i0 = ((size_t)blockIdx.x*256 + threadIdx.x) * 8;
    float4 a = *(const float4*)(X + i0);
    float4 b = *(const float4*)(X + i0 + 4);
    bf16x8 r = { f2bf(a.x), f2bf(a.y), f2bf(a.z), f2bf(a.w),
                 f2bf(b.x), f2bf(b.y), f2bf(b.z), f2bf(b.w) };
    *(bf16x8*)(Xb + i0) = r;
}

// ---------------- K0b: transpose-convert W[k][n] fp32 -> Wt[n][k] bf16 ----
__global__ __launch_bounds__(256) void k_cvt_wt(
    const float* __restrict__ Wq, const float* __restrict__ Wk,
    const float* __restrict__ Wv, const float* __restrict__ Wo,
    short* __restrict__ Wqt, short* __restrict__ Wkt,
    short* __restrict__ Wvt, short* __restrict__ Wot)
{
    const int z = blockIdx.z;
    const float* __restrict__ W = (z==0)?Wq:(z==1)?Wk:(z==2)?Wv:Wo;
    short* __restrict__ Wt      = (z==0)?Wqt:(z==1)?Wkt:(z==2)?Wvt:Wot;

    const int k0 = blockIdx.y * 32;
    const int n0 = blockIdx.x * 32;
    const int t  = threadIdx.x;

    __shared__ float Ls[32][33];
    {
        int row = t >> 3, col = (t & 7) * 4;
        *(float4*)&Ls[row][col] = *(const float4*)(W + (size_t)(k0+row)*EMB + n0 + col);
    }
    __syncthreads();
    {
        int n = t >> 3, k4 = (t & 7) * 4;
        bf16x4 r = { f2bf(Ls[k4+0][n]), f2bf(Ls[k4+1][n]),
                     f2bf(Ls[k4+2][n]), f2bf(Ls[k4+3][n]) };
        *(bf16x4*)(Wt + (size_t)(n0+n)*EMB + k0 + k4) = r;
    }
}

// ---------------- K1: QKV projection, bf16 MFMA 128x128xBK64 ---------------
// m97 structure: global_load_lds width=16 staging, linear [128][64] LDS
// (gload_lds needs contiguous dest; read conflicts accepted per regime gate).
__global__ __launch_bounds__(256) void k_gemm_qkv(
    const short* __restrict__ Xb,
    const short* __restrict__ Wqt, const short* __restrict__ Wkt, const short* __restrict__ Wvt,
    const float* __restrict__ bq, const float* __restrict__ bk, const float* __restrict__ bv,
    short* __restrict__ Qb, short* __restrict__ Kb, short* __restrict__ Vt)
{
    const int which = blockIdx.z;
    const short* __restrict__ Wt   = (which==0) ? Wqt : (which==1) ? Wkt : Wvt;
    const float* __restrict__ bias = (which==0) ? bq  : (which==1) ? bk  : bv;
    const float scale = (which==0) ? QSCALE : 1.0f;

    const int bm = blockIdx.y * 128;
    const int bn = blockIdx.x * 128;
    const int t    = threadIdx.x;
    const int wave = t >> 6, lane = t & 63;
    const int l16  = lane & 15, quad = lane >> 4;
    const int wm   = (wave >> 1) * 64, wn = (wave & 1) * 64;

    __shared__ short As[128][64];
    __shared__ short Bs[128][64];

    const int srow = lane >> 3;        // 0..7 within an 8-row segment
    const int scol = (lane & 7) * 8;   // 16B chunk

    f32x4 acc[4][4] = {};

    for (int kt = 0; kt < EMB; kt += 64) {
        __syncthreads();
        const short* Ag = Xb + (size_t)bm*EMB + kt;
        const short* Bg = Wt + (size_t)bn*EMB + kt;
        #pragma unroll
        for (int c = 0; c < 4; ++c) {
            int seg = wave*4 + c;               // 16 segments x 8 rows
            int grow = seg*8 + srow;
            glds16(Ag + (size_t)grow*EMB + scol, &As[seg*8][0]);
            glds16(Bg + (size_t)grow*EMB + scol, &Bs[seg*8][0]);
        }
        __syncthreads();
        #pragma unroll
        for (int ks = 0; ks < 64; ks += 32) {
            bf16x8 af[4], bfr[4];
            #pragma unroll
            for (int mi=0;mi<4;++mi) af[mi]  = *(const bf16x8*)&As[wm + mi*16 + l16][ks + quad*8];
            #pragma unroll
            for (int ni=0;ni<4;++ni) bfr[ni] = *(const bf16x8*)&Bs[wn + ni*16 + l16][ks + quad*8];
            #pragma unroll
            for (int mi=0;mi<4;++mi)
                #pragma unroll
                for (int ni=0;ni<4;++ni)
                    acc[mi][ni] = __builtin_amdgcn_mfma_f32_16x16x32_bf16(af[mi], bfr[ni], acc[mi][ni], 0,0,0);
        }
    }

    #pragma unroll
    for (int ni=0;ni<4;++ni) {
        int c = bn + wn + ni*16 + l16;
        float bval = bias[c];
        int h = c >> 6, d = c & 63;
        #pragma unroll
        for (int mi=0;mi<4;++mi) {
            #pragma unroll
            for (int j=0;j<4;++j) {
                int r = bm + wm + mi*16 + quad*4 + j;
                int tt = r >> 1, bb = r & 1;
                float val = (acc[mi][ni][j] + bval) * scale;
                if (which == 2)
                    Vt[((size_t)(bb*NH+h)*HD + d)*T_LEN + tt] = f2bf(val);
                else {
                    short* dst = (which==0) ? Qb : Kb;
                    dst[((size_t)(bb*NH+h)*T_LEN + tt)*HD + d] = f2bf(val);
                }
            }
        }
    }
}

// ---------------- K2: MFMA flash attention, no-max exp2 softmax -----------
// 8 waves x 16 q = 128 q-rows per block (512 threads): 2x the waves/SIMD of
// the 4-wave version -- the kernel was latency-bound at 2.5 waves/SIMD with
// every pipe <30% busy. Per-wave chain also halves. Double-buffered K/V LDS,
// register prefetch (T14), single barrier per tile, P never touches LDS
// (permuted-key A-fragment direct from softmax registers).
__global__ __launch_bounds__(512) void k_pv(
    const short* __restrict__ Qb, const short* __restrict__ Kb, const short* __restrict__ Vt,
    const int* __restrict__ kpm,
    float* __restrict__ Linv,
    short* __restrict__ AttnMidb)   // [4096][1280] bf16, r = t*BSZ + b
{
    const int qt = blockIdx.x;          // 16 tiles of 128 q
    const int bh = blockIdx.y;
    const int b  = bh / NH, h = bh % NH;
    const int t    = threadIdx.x;
    const int w    = t >> 6;            // 0..7
    const int lane = t & 63;
    const int l16  = lane & 15;
    const int quad = lane >> 4;
    const int q0   = qt*128 + w*16;     // wave's first q-row

    __shared__ short Ks[2][64][72];     // [buf][key][d]
    __shared__ short Vts[2][64][72];    // [buf][d][key]
    __shared__ float MfL[2][64];        // mask floats, double-buffered
    __shared__ float Lsh[128];

    // Q fragments resident: used as MFMA *B* operand (n=q, k=d)
    bf16x8 qf[2];
    #pragma unroll
    for (int ch=0;ch<2;++ch)
        qf[ch] = *(const bf16x8*)(Qb + ((size_t)bh*T_LEN + q0 + l16)*HD + ch*32 + quad*8);

    const int row0 = t >> 3, col8 = (t & 7) * 8;    // 512 threads cover 64 rows
    const short* Kgb = Kb + (size_t)bh*T_LEN*HD;
    const short* Vgb = Vt + (size_t)bh*HD*T_LEN;

    // prologue: stage tile 0 directly
    *(bf16x8*)&Ks[0][row0][col8]  = *(const bf16x8*)(Kgb + (size_t)row0*HD + col8);
    *(bf16x8*)&Vts[0][row0][col8] = *(const bf16x8*)(Vgb + (size_t)row0*T_LEN + col8);
    if (t < 64) MfL[0][t] = kpm[b*T_LEN + t] ? 0.f : 1.f;
    __syncthreads();

    f32x4 o[4] = {};                    // [d-block], C-layout
    float l = 0.f;                      // per-quad partial row sum
    int cur = 0;

    for (int kt = 0; kt < T_LEN; kt += 64) {
        const int ktn = kt + 64;
        const bool has_next = ktn < T_LEN;
        const int nxt = cur ^ 1;

        // T14: issue next tile's global loads NOW; ds_write after QK^T+softmax
        bf16x8 kr0, vr0;
        float mfn = 0.f;
        if (has_next) {
            kr0 = *(const bf16x8*)(Kgb + (size_t)(ktn + row0)*HD + col8);
            vr0 = *(const bf16x8*)(Vgb + (size_t)row0*T_LEN + ktn + col8);
            if (t < 64) mfn = kpm[b*T_LEN + ktn + t] ? 0.f : 1.f;
        }

        // S^T[key][q]: lane holds q = l16 (col), key = mb*16+quad*4+r (row)
        f32x4 s[4] = {};
        #pragma unroll
        for (int ch = 0; ch < 2; ++ch) {
            bf16x8 ka[4];
            #pragma unroll
            for (int mb=0;mb<4;++mb) ka[mb] = *(const bf16x8*)&Ks[cur][mb*16 + l16][ch*32 + quad*8];
            #pragma unroll
            for (int mb=0;mb<4;++mb)
                s[mb] = __builtin_amdgcn_mfma_f32_16x16x32_bf16(ka[mb], qf[ch], s[mb], 0,0,0);
        }

        // softmax fully in-register: p = exp2(s)*mask, accumulate l,
        // pack straight into PV A-fragment words (permuted key order).
        unsigned pu[2][4];              // [chunk][4 dwords = 8 bf16]
        #pragma unroll
        for (int c = 0; c < 2; ++c) {
            #pragma unroll
            for (int mb2 = 0; mb2 < 2; ++mb2) {
                const int mb = c*2 + mb2;
                float4 mf = *(const float4*)&MfL[cur][mb*16 + quad*4];
                float p0 = __builtin_amdgcn_exp2f(s[mb][0]) * mf.x;
                float p1 = __builtin_amdgcn_exp2f(s[mb][1]) * mf.y;
                float p2 = __builtin_amdgcn_exp2f(s[mb][2]) * mf.z;
                float p3 = __builtin_amdgcn_exp2f(s[mb][3]) * mf.w;
                l += (p0 + p1) + (p2 + p3);
                pu[c][mb2*2+0] = cvt_pk_bf16(p0, p1);
                pu[c][mb2*2+1] = cvt_pk_bf16(p2, p3);
            }
        }

        // write staged next tile (compiler inserts the vmcnt wait here)
        if (has_next) {
            *(bf16x8*)&Ks[nxt][row0][col8]  = kr0;
            *(bf16x8*)&Vts[nxt][row0][col8] = vr0;
            if (t < 64) MfL[nxt][t] = mfn;
        }

        // PV: B-fragment rows follow the same permuted key order
        #pragma unroll
        for (int c = 0; c < 2; ++c) {
            bf16x8 vv[4];
            #pragma unroll
            for (int nb=0;nb<4;++nb) {
                bf16x4 va = *(const bf16x4*)&Vts[cur][nb*16 + l16][c*32 + quad*4];
                bf16x4 vb = *(const bf16x4*)&Vts[cur][nb*16 + l16][c*32 + 16 + quad*4];
                vv[nb] = (bf16x8){va[0],va[1],va[2],va[3], vb[0],vb[1],vb[2],vb[3]};
            }
            union { unsigned u[4]; bf16x8 v; } pa;
            pa.u[0]=pu[c][0]; pa.u[1]=pu[c][1];
            pa.u[2]=pu[c][2]; pa.u[3]=pu[c][3];
            #pragma unroll
            for (int nb=0;nb<4;++nb)
                o[nb] = __builtin_amdgcn_mfma_f32_16x16x32_bf16(pa.v, vv[nb], o[nb], 0,0,0);
        }

        __syncthreads();   // single barrier per tile: nxt fully written, cur free
        cur = nxt;
    }

    // finalize l: reduce across quads (only cross-lane op in the kernel)
    l += __shfl_xor(l, 16);
    l += __shfl_xor(l, 32);
    float linv = 1.0f / l;
    if (quad == 0) {
        Linv[(size_t)bh*T_LEN + q0 + l16] = linv;
        Lsh[w*16 + l16] = linv;
    }
    // per-wave region of Lsh; same-wave ds ordering suffices (no barrier)
    {
        float4 li = *(const float4*)&Lsh[w*16 + quad*4];
        float lr[4] = {li.x, li.y, li.z, li.w};
        #pragma unroll
        for (int r=0;r<4;++r) {
            int q = q0 + quad*4 + r;
            size_t base = ((size_t)q*BSZ + b)*EMB + h*HD;
            #pragma unroll
            for (int nb=0;nb<4;++nb)
                AttnMidb[base + nb*16 + l16] = f2bf(o[nb][r] * lr[r]);
        }
    }
}

// ---------------- K3: avg_weights via MFMA, 64q x 64k tile ----------------
__global__ __launch_bounds__(256) void k_meanw(
    const short* __restrict__ Qb, const short* __restrict__ Kb,
    const int* __restrict__ kpm,
    const float* __restrict__ Linv,
    float* __restrict__ avg)   // [BSZ][T_LEN][T_LEN]
{
    const int kt = blockIdx.x;   // 32 k-tiles of 64
    const int qt = blockIdx.y;   // 32 q-tiles of 64
    const int b  = blockIdx.z;
    const int t    = threadIdx.x;
    const int wave = t >> 6, lane = t & 63;
    const int l16  = lane & 15, quad = lane >> 4;

    __shared__ short Qs[64][72];
    __shared__ short Ks[64][72];
    __shared__ float Lish[64];
    __shared__ int   msk[64];

    if (t < 64) msk[t] = kpm[b*T_LEN + kt*64 + t];

    f32x4 acc[4] = {};
    const int qrow_in = wave*16 + quad*4;   // + r

    for (int h = 0; h < NH; ++h) {
        const int bh = b*NH + h;
        __syncthreads();
        {
            const short* Qg = Qb + ((size_t)bh*T_LEN + qt*64)*HD;
            const short* Kg = Kb + ((size_t)bh*T_LEN + kt*64)*HD;
            #pragma unroll
            for (int c = 0; c < 2; ++c) {
                int idx = c*256 + t;
                int row = idx >> 3, col8 = (idx & 7) * 8;
                *(bf16x8*)&Qs[row][col8] = *(const bf16x8*)(Qg + (size_t)row*HD + col8);
                *(bf16x8*)&Ks[row][col8] = *(const bf16x8*)(Kg + (size_t)row*HD + col8);
            }
        }
        if (t < 64) Lish[t] = Linv[(size_t)bh*T_LEN + qt*64 + t];
        __syncthreads();

        bf16x8 aq0 = *(const bf16x8*)&Qs[wave*16 + l16][quad*8];
        bf16x8 aq1 = *(const bf16x8*)&Qs[wave*16 + l16][32 + quad*8];

        float lv[4];
        #pragma unroll
        for (int r = 0; r < 4; ++r)
            lv[r] = Lish[qrow_in + r] * (1.0f/NH);

        #pragma unroll
        for (int nb = 0; nb < 4; ++nb) {
            bf16x8 bk0 = *(const bf16x8*)&Ks[nb*16 + l16][quad*8];
            bf16x8 bk1 = *(const bf16x8*)&Ks[nb*16 + l16][32 + quad*8];
            f32x4 s = {};
            s = __builtin_amdgcn_mfma_f32_16x16x32_bf16(aq0, bk0, s, 0,0,0);
            s = __builtin_amdgcn_mfma_f32_16x16x32_bf16(aq1, bk1, s, 0,0,0);
            const bool mk = msk[nb*16 + l16] != 0;
            #pragma unroll
            for (int r = 0; r < 4; ++r)
                acc[nb][r] += mk ? 0.f : __builtin_amdgcn_exp2f(s[r]) * lv[r];
        }
    }

    #pragma unroll
    for (int r = 0; r < 4; ++r) {
        int q = qt*64 + qrow_in + r;
        size_t base = ((size_t)b*T_LEN + q) * T_LEN + (size_t)kt*64;
        #pragma unroll
        for (int nb = 0; nb < 4; ++nb)
            avg[base + nb*16 + l16] = acc[nb][r];
    }
}

// ---------------- K4: output projection, bf16 MFMA 128x128xBK64 ------------
__global__ __launch_bounds__(256) void k_gemm_out(
    const short* __restrict__ Ab, const short* __restrict__ Wot,
    const float* __restrict__ bo, float* __restrict__ out)
{
    const int bm = blockIdx.y * 128;
    const int bn = blockIdx.x * 128;
    const int t    = threadIdx.x;
    const int wave = t >> 6, lane = t & 63;
    const int l16  = lane & 15, quad = lane >> 4;
    const int wm   = (wave >> 1) * 64, wn = (wave & 1) * 64;

    __shared__ short As[128][64];
    __shared__ short Bs[128][64];

    const int srow = lane >> 3;
    const int scol = (lane & 7) * 8;

    f32x4 acc[4][4] = {};

    for (int kt = 0; kt < EMB; kt += 64) {
        __syncthreads();
        const short* Ag = Ab  + (size_t)bm*EMB + kt;
        const short* Bg = Wot + (size_t)bn*EMB + kt;
        #pragma unroll
        for (int c = 0; c < 4; ++c) {
            int seg = wave*4 + c;
            int grow = seg*8 + srow;
            glds16(Ag + (size_t)grow*EMB + scol, &As[seg*8][0]);
            glds16(Bg + (size_t)grow*EMB + scol, &Bs[seg*8][0]);
        }
        __syncthreads();
        #pragma unroll
        for (int ks = 0; ks < 64; ks += 32) {
            bf16x8 af[4], bfr[4];
            #pragma unroll
            for (int mi=0;mi<4;++mi) af[mi]  = *(const bf16x8*)&As[wm + mi*16 + l16][ks + quad*8];
            #pragma unroll
            for (int ni=0;ni<4;++ni) bfr[ni] = *(const bf16x8*)&Bs[wn + ni*16 + l16][ks + quad*8];
            #pragma unroll
            for (int mi=0;mi<4;++mi)
                #pragma unroll
                for (int ni=0;ni<4;++ni)
                    acc[mi][ni] = __builtin_amdgcn_mfma_f32_16x16x32_bf16(af[mi], bfr[ni], acc[mi][ni], 0,0,0);
        }
    }

    #pragma unroll
    for (int ni=0;ni<4;++ni) {
        int c = bn + wn + ni*16 + l16;
        float bval = bo[c];
        #pragma unroll
        for (int mi=0;mi<4;++mi) {
            #pragma unroll
            for (int j=0;j<4;++j) {
                int r = bm + wm + mi*16 + quad*4 + j;
                out[(size_t)r*EMB + c] = acc[mi][ni][j] + bval;
            }
        }
    }
}

extern "C" void kernel_launch(void* const* d_in, const int* in_sizes, int n_in,
                              void* d_out, int out_size, void* d_ws, size_t ws_size,
                              hipStream_t stream) {
    const float* X   = (const float*)d_in[0];
    const int*   kpm = (const int*)  d_in[1];
    const float* Wq  = (const float*)d_in[2];
    const float* bq  = (const float*)d_in[3];
    const float* Wk  = (const float*)d_in[4];
    const float* bk  = (const float*)d_in[5];
    const float* Wv  = (const float*)d_in[6];
    const float* bv  = (const float*)d_in[7];
    const float* Wo  = (const float*)d_in[8];
    const float* bo  = (const float*)d_in[9];

    float* out = (float*)d_out;
    float* ws  = (float*)d_ws;

    const size_t QKV = (size_t)NBH * T_LEN * HD;   // 5,242,880
    float* Linv = ws;
    short* Xb   = (short*)(Linv + (size_t)NBH * T_LEN);
    short* Wqt  = Xb  + (size_t)NR * EMB;
    short* Wkt  = Wqt + (size_t)EMB * EMB;
    short* Wvt  = Wkt + (size_t)EMB * EMB;
    short* Wot  = Wvt + (size_t)EMB * EMB;
    short* Qb   = Wot + (size_t)EMB * EMB;
    short* Kb   = Qb  + QKV;
    short* Vt   = Kb  + QKV;
    short* Amid = Vt  + QKV;

    float* attn_out = out;                              // [T_LEN, BSZ, EMB]
    float* avg      = out + (size_t)T_LEN * BSZ * EMB;  // [BSZ, T_LEN, T_LEN]

    k_cvt_x   <<<dim3((NR*EMB)/(256*8)), 256, 0, stream>>>(X, Xb);
    k_cvt_wt  <<<dim3(EMB/32, EMB/32, 4), 256, 0, stream>>>(Wq, Wk, Wv, Wo, Wqt, Wkt, Wvt, Wot);
    k_gemm_qkv<<<dim3(EMB/128, NR/128, 3), 256, 0, stream>>>(Xb, Wqt, Wkt, Wvt, bq, bk, bv, Qb, Kb, Vt);
    k_pv      <<<dim3(T_LEN/128, NBH),   512, 0, stream>>>(Qb, Kb, Vt, kpm, Linv, Amid);
    k_meanw   <<<dim3(T_LEN/64, T_LEN/64, BSZ), 256, 0, stream>>>(Qb, Kb, kpm, Linv, avg);
    k_gemm_out<<<dim3(EMB/128, NR/128),  256, 0, stream>>>(Amid, Wot, bo, attn_out);
}

// Round 3
// 345.821 us; speedup vs baseline: 1.0799x; 1.0799x over previous
//
#include <hip/hip_runtime.h>

#define T_LEN 2048
#define BSZ   2
#define EMB   1280
#define NH    20
#define HD    64
#define NBH   (BSZ*NH)      // 40
#define NR    (T_LEN*BSZ)   // 4096
// HEAD_DIM^-0.5 * (1/ln2): scores computed in log2 domain -> raw v_exp_f32.
// exp2(s/ln2) == exp(s) exactly; Linv/meanw use the same convention.
#define QSCALE (0.125f * 1.4426950408889634f)

// LDS pad: stride 68 shorts = 136 B = 34 banks -> 2 banks/row: all 16 l16
// rows land on distinct banks for strided b128 fragment reads (was 72 =
// 144 B = 4 banks/row -> 8-way conflict, 2.94x per m136).
#define KPAD 68

typedef short bf16x8 __attribute__((ext_vector_type(8)));
typedef short bf16x4 __attribute__((ext_vector_type(4)));
typedef float f32x4  __attribute__((ext_vector_type(4)));

__device__ inline short f2bf(float f) {
    union { float f; unsigned u; } v; v.f = f;
    unsigned u = v.u + 0x7FFF + ((v.u >> 16) & 1);
    return (short)(u >> 16);
}

// packed f32->bf16 convert (RNE), no builtin on gfx950 -> inline asm (T12)
__device__ inline unsigned cvt_pk_bf16(float lo, float hi) {
    unsigned r;
    asm("v_cvt_pk_bf16_f32 %0, %1, %2" : "=v"(r) : "v"(lo), "v"(hi));
    return r;
}

// async global->LDS, 16B per lane. LDS dest: wave-uniform base + lane*16.
__device__ inline void glds16(const short* g, short* l) {
    __builtin_amdgcn_global_load_lds(
        (const __attribute__((address_space(1))) void*)g,
        (__attribute__((address_space(3))) void*)l,
        16, 0, 0);
}

// ---------------- K0a: convert X -> bf16 ----------------
__global__ __launch_bounds__(256) void k_cvt_x(
    const float* __restrict__ X, short* __restrict__ Xb)
{
    size_t i0 = ((size_t)blockIdx.x*256 + threadIdx.x) * 8;
    float4 a = *(const float4*)(X + i0);
    float4 b = *(const float4*)(X + i0 + 4);
    bf16x8 r = { f2bf(a.x), f2bf(a.y), f2bf(a.z), f2bf(a.w),
                 f2bf(b.x), f2bf(b.y), f2bf(b.z), f2bf(b.w) };
    *(bf16x8*)(Xb + i0) = r;
}

// ---------------- K0b: transpose-convert W[k][n] fp32 -> Wt[n][k] bf16 ----
__global__ __launch_bounds__(256) void k_cvt_wt(
    const float* __restrict__ Wq, const float* __restrict__ Wk,
    const float* __restrict__ Wv, const float* __restrict__ Wo,
    short* __restrict__ Wqt, short* __restrict__ Wkt,
    short* __restrict__ Wvt, short* __restrict__ Wot)
{
    const int z = blockIdx.z;
    const float* __restrict__ W = (z==0)?Wq:(z==1)?Wk:(z==2)?Wv:Wo;
    short* __restrict__ Wt      = (z==0)?Wqt:(z==1)?Wkt:(z==2)?Wvt:Wot;

    const int k0 = blockIdx.y * 32;
    const int n0 = blockIdx.x * 32;
    const int t  = threadIdx.x;

    __shared__ float Ls[32][33];
    {
        int row = t >> 3, col = (t & 7) * 4;
        *(float4*)&Ls[row][col] = *(const float4*)(W + (size_t)(k0+row)*EMB + n0 + col);
    }
    __syncthreads();
    {
        int n = t >> 3, k4 = (t & 7) * 4;
        bf16x4 r = { f2bf(Ls[k4+0][n]), f2bf(Ls[k4+1][n]),
                     f2bf(Ls[k4+2][n]), f2bf(Ls[k4+3][n]) };
        *(bf16x4*)(Wt + (size_t)(n0+n)*EMB + k0 + k4) = r;
    }
}

// ---------------- K1: QKV projection, bf16 MFMA 128x128xBK64 ---------------
// m97 structure + T21 both-sides XOR swizzle: gload_lds dest stays linear,
// global SOURCE 16B-chunk is pre-swizzled by row&7, fragment reads XOR the
// column with (l16&7)<<3 -> 16-way read conflict of linear [128][64] killed.
__global__ __launch_bounds__(256) void k_gemm_qkv(
    const short* __restrict__ Xb,
    const short* __restrict__ Wqt, const short* __restrict__ Wkt, const short* __restrict__ Wvt,
    const float* __restrict__ bq, const float* __restrict__ bk, const float* __restrict__ bv,
    short* __restrict__ Qb, short* __restrict__ Kb, short* __restrict__ Vt)
{
    const int which = blockIdx.z;
    const short* __restrict__ Wt   = (which==0) ? Wqt : (which==1) ? Wkt : Wvt;
    const float* __restrict__ bias = (which==0) ? bq  : (which==1) ? bk  : bv;
    const float scale = (which==0) ? QSCALE : 1.0f;

    const int bm = blockIdx.y * 128;
    const int bn = blockIdx.x * 128;
    const int t    = threadIdx.x;
    const int wave = t >> 6, lane = t & 63;
    const int l16  = lane & 15, quad = lane >> 4;
    const int wm   = (wave >> 1) * 64, wn = (wave & 1) * 64;

    __shared__ short As[128][64];
    __shared__ short Bs[128][64];

    const int srow   = lane >> 3;                       // 0..7 in segment
    const int scolsw = (((lane & 7) ^ srow) & 7) * 8;   // pre-swizzled 16B chunk
    const int rsw    = (l16 & 7) << 3;                  // read-side XOR (shorts)

    f32x4 acc[4][4] = {};

    for (int kt = 0; kt < EMB; kt += 64) {
        __syncthreads();
        const short* Ag = Xb + (size_t)bm*EMB + kt;
        const short* Bg = Wt + (size_t)bn*EMB + kt;
        #pragma unroll
        for (int c = 0; c < 4; ++c) {
            int seg = wave*4 + c;               // 16 segments x 8 rows
            int grow = seg*8 + srow;
            glds16(Ag + (size_t)grow*EMB + scolsw, &As[seg*8][0]);
            glds16(Bg + (size_t)grow*EMB + scolsw, &Bs[seg*8][0]);
        }
        __syncthreads();
        #pragma unroll
        for (int ks = 0; ks < 64; ks += 32) {
            bf16x8 af[4], bfr[4];
            #pragma unroll
            for (int mi=0;mi<4;++mi) af[mi]  = *(const bf16x8*)&As[wm + mi*16 + l16][(ks + quad*8) ^ rsw];
            #pragma unroll
            for (int ni=0;ni<4;++ni) bfr[ni] = *(const bf16x8*)&Bs[wn + ni*16 + l16][(ks + quad*8) ^ rsw];
            #pragma unroll
            for (int mi=0;mi<4;++mi)
                #pragma unroll
                for (int ni=0;ni<4;++ni)
                    acc[mi][ni] = __builtin_amdgcn_mfma_f32_16x16x32_bf16(af[mi], bfr[ni], acc[mi][ni], 0,0,0);
        }
    }

    #pragma unroll
    for (int ni=0;ni<4;++ni) {
        int c = bn + wn + ni*16 + l16;
        float bval = bias[c];
        int h = c >> 6, d = c & 63;
        #pragma unroll
        for (int mi=0;mi<4;++mi) {
            #pragma unroll
            for (int j=0;j<4;++j) {
                int r = bm + wm + mi*16 + quad*4 + j;
                int tt = r >> 1, bb = r & 1;
                float val = (acc[mi][ni][j] + bval) * scale;
                if (which == 2)
                    Vt[((size_t)(bb*NH+h)*HD + d)*T_LEN + tt] = f2bf(val);
                else {
                    short* dst = (which==0) ? Qb : Kb;
                    dst[((size_t)(bb*NH+h)*T_LEN + tt)*HD + d] = f2bf(val);
                }
            }
        }
    }
}

// ---------------- K2: MFMA flash attention, no-max exp2 softmax -----------
// 8 waves x 16 q = 128 q-rows (512 threads). Double-buffered K/V LDS with
// register prefetch (T14), single barrier per tile, P never touches LDS.
// KPAD=68 kills the 8-way bank conflict on the K-fragment b128 reads.
__global__ __launch_bounds__(512) void k_pv(
    const short* __restrict__ Qb, const short* __restrict__ Kb, const short* __restrict__ Vt,
    const int* __restrict__ kpm,
    float* __restrict__ Linv,
    short* __restrict__ AttnMidb)   // [4096][1280] bf16, r = t*BSZ + b
{
    const int qt = blockIdx.x;          // 16 tiles of 128 q
    const int bh = blockIdx.y;
    const int b  = bh / NH, h = bh % NH;
    const int t    = threadIdx.x;
    const int w    = t >> 6;            // 0..7
    const int lane = t & 63;
    const int l16  = lane & 15;
    const int quad = lane >> 4;
    const int q0   = qt*128 + w*16;     // wave's first q-row

    __shared__ short Ks[2][64][KPAD];   // [buf][key][d]
    __shared__ short Vts[2][64][KPAD];  // [buf][d][key]
    __shared__ float MfL[2][64];        // mask floats, double-buffered
    __shared__ float Lsh[128];

    // Q fragments resident: used as MFMA *B* operand (n=q, k=d)
    bf16x8 qf[2];
    #pragma unroll
    for (int ch=0;ch<2;++ch)
        qf[ch] = *(const bf16x8*)(Qb + ((size_t)bh*T_LEN + q0 + l16)*HD + ch*32 + quad*8);

    const int row0 = t >> 3, col8 = (t & 7) * 8;    // 512 threads cover 64 rows
    const short* Kgb = Kb + (size_t)bh*T_LEN*HD;
    const short* Vgb = Vt + (size_t)bh*HD*T_LEN;

    // prologue: stage tile 0 directly
    *(bf16x8*)&Ks[0][row0][col8]  = *(const bf16x8*)(Kgb + (size_t)row0*HD + col8);
    *(bf16x8*)&Vts[0][row0][col8] = *(const bf16x8*)(Vgb + (size_t)row0*T_LEN + col8);
    if (t < 64) MfL[0][t] = kpm[b*T_LEN + t] ? 0.f : 1.f;
    __syncthreads();

    f32x4 o[4] = {};                    // [d-block], C-layout
    float l = 0.f;                      // per-quad partial row sum
    int cur = 0;

    for (int kt = 0; kt < T_LEN; kt += 64) {
        const int ktn = kt + 64;
        const bool has_next = ktn < T_LEN;
        const int nxt = cur ^ 1;

        // T14: issue next tile's global loads NOW; ds_write after QK^T+softmax
        bf16x8 kr0, vr0;
        float mfn = 0.f;
        if (has_next) {
            kr0 = *(const bf16x8*)(Kgb + (size_t)(ktn + row0)*HD + col8);
            vr0 = *(const bf16x8*)(Vgb + (size_t)row0*T_LEN + ktn + col8);
            if (t < 64) mfn = kpm[b*T_LEN + ktn + t] ? 0.f : 1.f;
        }

        // S^T[key][q]: lane holds q = l16 (col), key = mb*16+quad*4+r (row)
        f32x4 s[4] = {};
        #pragma unroll
        for (int ch = 0; ch < 2; ++ch) {
            bf16x8 ka[4];
            #pragma unroll
            for (int mb=0;mb<4;++mb) ka[mb] = *(const bf16x8*)&Ks[cur][mb*16 + l16][ch*32 + quad*8];
            #pragma unroll
            for (int mb=0;mb<4;++mb)
                s[mb] = __builtin_amdgcn_mfma_f32_16x16x32_bf16(ka[mb], qf[ch], s[mb], 0,0,0);
        }

        // softmax fully in-register: p = exp2(s)*mask, accumulate l,
        // pack straight into PV A-fragment words (permuted key order).
        unsigned pu[2][4];              // [chunk][4 dwords = 8 bf16]
        #pragma unroll
        for (int c = 0; c < 2; ++c) {
            #pragma unroll
            for (int mb2 = 0; mb2 < 2; ++mb2) {
                const int mb = c*2 + mb2;
                float4 mf = *(const float4*)&MfL[cur][mb*16 + quad*4];
                float p0 = __builtin_amdgcn_exp2f(s[mb][0]) * mf.x;
                float p1 = __builtin_amdgcn_exp2f(s[mb][1]) * mf.y;
                float p2 = __builtin_amdgcn_exp2f(s[mb][2]) * mf.z;
                float p3 = __builtin_amdgcn_exp2f(s[mb][3]) * mf.w;
                l += (p0 + p1) + (p2 + p3);
                pu[c][mb2*2+0] = cvt_pk_bf16(p0, p1);
                pu[c][mb2*2+1] = cvt_pk_bf16(p2, p3);
            }
        }

        // write staged next tile (compiler inserts the vmcnt wait here)
        if (has_next) {
            *(bf16x8*)&Ks[nxt][row0][col8]  = kr0;
            *(bf16x8*)&Vts[nxt][row0][col8] = vr0;
            if (t < 64) MfL[nxt][t] = mfn;
        }

        // PV: B-fragment rows follow the same permuted key order
        #pragma unroll
        for (int c = 0; c < 2; ++c) {
            bf16x8 vv[4];
            #pragma unroll
            for (int nb=0;nb<4;++nb) {
                bf16x4 va = *(const bf16x4*)&Vts[cur][nb*16 + l16][c*32 + quad*4];
                bf16x4 vb = *(const bf16x4*)&Vts[cur][nb*16 + l16][c*32 + 16 + quad*4];
                vv[nb] = (bf16x8){va[0],va[1],va[2],va[3], vb[0],vb[1],vb[2],vb[3]};
            }
            union { unsigned u[4]; bf16x8 v; } pa;
            pa.u[0]=pu[c][0]; pa.u[1]=pu[c][1];
            pa.u[2]=pu[c][2]; pa.u[3]=pu[c][3];
            #pragma unroll
            for (int nb=0;nb<4;++nb)
                o[nb] = __builtin_amdgcn_mfma_f32_16x16x32_bf16(pa.v, vv[nb], o[nb], 0,0,0);
        }

        __syncthreads();   // single barrier per tile: nxt fully written, cur free
        cur = nxt;
    }

    // finalize l: reduce across quads (only cross-lane op in the kernel)
    l += __shfl_xor(l, 16);
    l += __shfl_xor(l, 32);
    float linv = 1.0f / l;
    if (quad == 0) {
        Linv[(size_t)bh*T_LEN + q0 + l16] = linv;
        Lsh[w*16 + l16] = linv;
    }
    // per-wave region of Lsh; same-wave ds ordering suffices (no barrier)
    {
        float4 li = *(const float4*)&Lsh[w*16 + quad*4];
        float lr[4] = {li.x, li.y, li.z, li.w};
        #pragma unroll
        for (int r=0;r<4;++r) {
            int q = q0 + quad*4 + r;
            size_t base = ((size_t)q*BSZ + b)*EMB + h*HD;
            #pragma unroll
            for (int nb=0;nb<4;++nb)
                AttnMidb[base + nb*16 + l16] = f2bf(o[nb][r] * lr[r]);
        }
    }
}

// ---------------- K3: avg_weights via MFMA, 64q x 64k tile ----------------
__global__ __launch_bounds__(256) void k_meanw(
    const short* __restrict__ Qb, const short* __restrict__ Kb,
    const int* __restrict__ kpm,
    const float* __restrict__ Linv,
    float* __restrict__ avg)   // [BSZ][T_LEN][T_LEN]
{
    const int kt = blockIdx.x;   // 32 k-tiles of 64
    const int qt = blockIdx.y;   // 32 q-tiles of 64
    const int b  = blockIdx.z;
    const int t    = threadIdx.x;
    const int wave = t >> 6, lane = t & 63;
    const int l16  = lane & 15, quad = lane >> 4;

    __shared__ short Qs[64][KPAD];
    __shared__ short Ks[64][KPAD];
    __shared__ float Lish[64];
    __shared__ int   msk[64];

    if (t < 64) msk[t] = kpm[b*T_LEN + kt*64 + t];

    f32x4 acc[4] = {};
    const int qrow_in = wave*16 + quad*4;   // + r

    for (int h = 0; h < NH; ++h) {
        const int bh = b*NH + h;
        __syncthreads();
        {
            const short* Qg = Qb + ((size_t)bh*T_LEN + qt*64)*HD;
            const short* Kg = Kb + ((size_t)bh*T_LEN + kt*64)*HD;
            #pragma unroll
            for (int c = 0; c < 2; ++c) {
                int idx = c*256 + t;
                int row = idx >> 3, col8 = (idx & 7) * 8;
                *(bf16x8*)&Qs[row][col8] = *(const bf16x8*)(Qg + (size_t)row*HD + col8);
                *(bf16x8*)&Ks[row][col8] = *(const bf16x8*)(Kg + (size_t)row*HD + col8);
            }
        }
        if (t < 64) Lish[t] = Linv[(size_t)bh*T_LEN + qt*64 + t];
        __syncthreads();

        bf16x8 aq0 = *(const bf16x8*)&Qs[wave*16 + l16][quad*8];
        bf16x8 aq1 = *(const bf16x8*)&Qs[wave*16 + l16][32 + quad*8];

        float lv[4];
        #pragma unroll
        for (int r = 0; r < 4; ++r)
            lv[r] = Lish[qrow_in + r] * (1.0f/NH);

        #pragma unroll
        for (int nb = 0; nb < 4; ++nb) {
            bf16x8 bk0 = *(const bf16x8*)&Ks[nb*16 + l16][quad*8];
            bf16x8 bk1 = *(const bf16x8*)&Ks[nb*16 + l16][32 + quad*8];
            f32x4 s = {};
            s = __builtin_amdgcn_mfma_f32_16x16x32_bf16(aq0, bk0, s, 0,0,0);
            s = __builtin_amdgcn_mfma_f32_16x16x32_bf16(aq1, bk1, s, 0,0,0);
            const bool mk = msk[nb*16 + l16] != 0;
            #pragma unroll
            for (int r = 0; r < 4; ++r)
                acc[nb][r] += mk ? 0.f : __builtin_amdgcn_exp2f(s[r]) * lv[r];
        }
    }

    #pragma unroll
    for (int r = 0; r < 4; ++r) {
        int q = qt*64 + qrow_in + r;
        size_t base = ((size_t)b*T_LEN + q) * T_LEN + (size_t)kt*64;
        #pragma unroll
        for (int nb = 0; nb < 4; ++nb)
            avg[base + nb*16 + l16] = acc[nb][r];
    }
}

// ---------------- K4: output projection, bf16 MFMA 128x128xBK64 ------------
__global__ __launch_bounds__(256) void k_gemm_out(
    const short* __restrict__ Ab, const short* __restrict__ Wot,
    const float* __restrict__ bo, float* __restrict__ out)
{
    const int bm = blockIdx.y * 128;
    const int bn = blockIdx.x * 128;
    const int t    = threadIdx.x;
    const int wave = t >> 6, lane = t & 63;
    const int l16  = lane & 15, quad = lane >> 4;
    const int wm   = (wave >> 1) * 64, wn = (wave & 1) * 64;

    __shared__ short As[128][64];
    __shared__ short Bs[128][64];

    const int srow   = lane >> 3;
    const int scolsw = (((lane & 7) ^ srow) & 7) * 8;
    const int rsw    = (l16 & 7) << 3;

    f32x4 acc[4][4] = {};

    for (int kt = 0; kt < EMB; kt += 64) {
        __syncthreads();
        const short* Ag = Ab  + (size_t)bm*EMB + kt;
        const short* Bg = Wot + (size_t)bn*EMB + kt;
        #pragma unroll
        for (int c = 0; c < 4; ++c) {
            int seg = wave*4 + c;
            int grow = seg*8 + srow;
            glds16(Ag + (size_t)grow*EMB + scolsw, &As[seg*8][0]);
            glds16(Bg + (size_t)grow*EMB + scolsw, &Bs[seg*8][0]);
        }
        __syncthreads();
        #pragma unroll
        for (int ks = 0; ks < 64; ks += 32) {
            bf16x8 af[4], bfr[4];
            #pragma unroll
            for (int mi=0;mi<4;++mi) af[mi]  = *(const bf16x8*)&As[wm + mi*16 + l16][(ks + quad*8) ^ rsw];
            #pragma unroll
            for (int ni=0;ni<4;++ni) bfr[ni] = *(const bf16x8*)&Bs[wn + ni*16 + l16][(ks + quad*8) ^ rsw];
            #pragma unroll
            for (int mi=0;mi<4;++mi)
                #pragma unroll
                for (int ni=0;ni<4;++ni)
                    acc[mi][ni] = __builtin_amdgcn_mfma_f32_16x16x32_bf16(af[mi], bfr[ni], acc[mi][ni], 0,0,0);
        }
    }

    #pragma unroll
    for (int ni=0;ni<4;++ni) {
        int c = bn + wn + ni*16 + l16;
        float bval = bo[c];
        #pragma unroll
        for (int mi=0;mi<4;++mi) {
            #pragma unroll
            for (int j=0;j<4;++j) {
                int r = bm + wm + mi*16 + quad*4 + j;
                out[(size_t)r*EMB + c] = acc[mi][ni][j] + bval;
            }
        }
    }
}

extern "C" void kernel_launch(void* const* d_in, const int* in_sizes, int n_in,
                              void* d_out, int out_size, void* d_ws, size_t ws_size,
                              hipStream_t stream) {
    const float* X   = (const float*)d_in[0];
    const int*   kpm = (const int*)  d_in[1];
    const float* Wq  = (const float*)d_in[2];
    const float* bq  = (const float*)d_in[3];
    const float* Wk  = (const float*)d_in[4];
    const float* bk  = (const float*)d_in[5];
    const float* Wv  = (const float*)d_in[6];
    const float* bv  = (const float*)d_in[7];
    const float* Wo  = (const float*)d_in[8];
    const float* bo  = (const float*)d_in[9];

    float* out = (float*)d_out;
    float* ws  = (float*)d_ws;

    const size_t QKV = (size_t)NBH * T_LEN * HD;   // 5,242,880
    float* Linv = ws;
    short* Xb   = (short*)(Linv + (size_t)NBH * T_LEN);
    short* Wqt  = Xb  + (size_t)NR * EMB;
    short* Wkt  = Wqt + (size_t)EMB * EMB;
    short* Wvt  = Wkt + (size_t)EMB * EMB;
    short* Wot  = Wvt + (size_t)EMB * EMB;
    short* Qb   = Wot + (size_t)EMB * EMB;
    short* Kb   = Qb  + QKV;
    short* Vt   = Kb  + QKV;
    short* Amid = Vt  + QKV;

    float* attn_out = out;                              // [T_LEN, BSZ, EMB]
    float* avg      = out + (size_t)T_LEN * BSZ * EMB;  // [BSZ, T_LEN, T_LEN]

    k_cvt_x   <<<dim3((NR*EMB)/(256*8)), 256, 0, stream>>>(X, Xb);
    k_cvt_wt  <<<dim3(EMB/32, EMB/32, 4), 256, 0, stream>>>(Wq, Wk, Wv, Wo, Wqt, Wkt, Wvt, Wot);
    k_gemm_qkv<<<dim3(EMB/128, NR/128, 3), 256, 0, stream>>>(Xb, Wqt, Wkt, Wvt, bq, bk, bv, Qb, Kb, Vt);
    k_pv      <<<dim3(T_LEN/128, NBH),   512, 0, stream>>>(Qb, Kb, Vt, kpm, Linv, Amid);
    k_meanw   <<<dim3(T_LEN/64, T_LEN/64, BSZ), 256, 0, stream>>>(Qb, Kb, kpm, Linv, avg);
    k_gemm_out<<<dim3(EMB/128, NR/128),  256, 0, stream>>>(Amid, Wot, bo, attn_out);
}

// Round 4
// 341.237 us; speedup vs baseline: 1.0944x; 1.0134x over previous
//
#include <hip/hip_runtime.h>

#define T_LEN 2048
#define BSZ   2
#define EMB   1280
#define NH    20
#define HD    64
#define NBH   (BSZ*NH)      // 40
#define NR    (T_LEN*BSZ)   // 4096
// HEAD_DIM^-0.5 * (1/ln2): scores computed in log2 domain -> raw v_exp_f32.
// exp2(s/ln2) == exp(s) exactly; Linv/meanw use the same convention.
#define QSCALE (0.125f * 1.4426950408889634f)

// LDS pad: stride 68 shorts = 136 B = 34 banks -> 2 banks/row: all 16 l16
// rows land on distinct banks for strided b128 fragment reads (was 72 =
// 144 B = 4 banks/row -> 8-way conflict; fix measured: conflicts -> 0).
#define KPAD 68

typedef short bf16x8 __attribute__((ext_vector_type(8)));
typedef short bf16x4 __attribute__((ext_vector_type(4)));
typedef float f32x4  __attribute__((ext_vector_type(4)));

__device__ inline short f2bf(float f) {
    union { float f; unsigned u; } v; v.f = f;
    unsigned u = v.u + 0x7FFF + ((v.u >> 16) & 1);
    return (short)(u >> 16);
}

// packed f32->bf16 convert (RNE), no builtin on gfx950 -> inline asm (T12)
__device__ inline unsigned cvt_pk_bf16(float lo, float hi) {
    unsigned r;
    asm("v_cvt_pk_bf16_f32 %0, %1, %2" : "=v"(r) : "v"(lo), "v"(hi));
    return r;
}

// async global->LDS, 16B per lane. LDS dest: wave-uniform base + lane*16.
__device__ inline void glds16(const short* g, short* l) {
    __builtin_amdgcn_global_load_lds(
        (const __attribute__((address_space(1))) void*)g,
        (__attribute__((address_space(3))) void*)l,
        16, 0, 0);
}

// ---------------- K0a: convert X -> bf16 ----------------
__global__ __launch_bounds__(256) void k_cvt_x(
    const float* __restrict__ X, short* __restrict__ Xb)
{
    size_t i0 = ((size_t)blockIdx.x*256 + threadIdx.x) * 8;
    float4 a = *(const float4*)(X + i0);
    float4 b = *(const float4*)(X + i0 + 4);
    bf16x8 r = { f2bf(a.x), f2bf(a.y), f2bf(a.z), f2bf(a.w),
                 f2bf(b.x), f2bf(b.y), f2bf(b.z), f2bf(b.w) };
    *(bf16x8*)(Xb + i0) = r;
}

// ---------------- K0b: transpose-convert W[k][n] fp32 -> Wt[n][k] bf16 ----
__global__ __launch_bounds__(256) void k_cvt_wt(
    const float* __restrict__ Wq, const float* __restrict__ Wk,
    const float* __restrict__ Wv, const float* __restrict__ Wo,
    short* __restrict__ Wqt, short* __restrict__ Wkt,
    short* __restrict__ Wvt, short* __restrict__ Wot)
{
    const int z = blockIdx.z;
    const float* __restrict__ W = (z==0)?Wq:(z==1)?Wk:(z==2)?Wv:Wo;
    short* __restrict__ Wt      = (z==0)?Wqt:(z==1)?Wkt:(z==2)?Wvt:Wot;

    const int k0 = blockIdx.y * 32;
    const int n0 = blockIdx.x * 32;
    const int t  = threadIdx.x;

    __shared__ float Ls[32][33];
    {
        int row = t >> 3, col = (t & 7) * 4;
        *(float4*)&Ls[row][col] = *(const float4*)(W + (size_t)(k0+row)*EMB + n0 + col);
    }
    __syncthreads();
    {
        int n = t >> 3, k4 = (t & 7) * 4;
        bf16x4 r = { f2bf(Ls[k4+0][n]), f2bf(Ls[k4+1][n]),
                     f2bf(Ls[k4+2][n]), f2bf(Ls[k4+3][n]) };
        *(bf16x4*)(Wt + (size_t)(n0+n)*EMB + k0 + k4) = r;
    }
}

// ---------------- K1: QKV projection, bf16 MFMA 128x128xBK64 ---------------
// m97 structure + T21 both-sides XOR swizzle: gload_lds dest stays linear,
// global SOURCE 16B-chunk is pre-swizzled by row&7, fragment reads XOR the
// column with (l16&7)<<3.
__global__ __launch_bounds__(256) void k_gemm_qkv(
    const short* __restrict__ Xb,
    const short* __restrict__ Wqt, const short* __restrict__ Wkt, const short* __restrict__ Wvt,
    const float* __restrict__ bq, const float* __restrict__ bk, const float* __restrict__ bv,
    short* __restrict__ Qb, short* __restrict__ Kb, short* __restrict__ Vt)
{
    const int which = blockIdx.z;
    const short* __restrict__ Wt   = (which==0) ? Wqt : (which==1) ? Wkt : Wvt;
    const float* __restrict__ bias = (which==0) ? bq  : (which==1) ? bk  : bv;
    const float scale = (which==0) ? QSCALE : 1.0f;

    const int bm = blockIdx.y * 128;
    const int bn = blockIdx.x * 128;
    const int t    = threadIdx.x;
    const int wave = t >> 6, lane = t & 63;
    const int l16  = lane & 15, quad = lane >> 4;
    const int wm   = (wave >> 1) * 64, wn = (wave & 1) * 64;

    __shared__ short As[128][64];
    __shared__ short Bs[128][64];

    const int srow   = lane >> 3;                       // 0..7 in segment
    const int scolsw = (((lane & 7) ^ srow) & 7) * 8;   // pre-swizzled 16B chunk
    const int rsw    = (l16 & 7) << 3;                  // read-side XOR (shorts)

    f32x4 acc[4][4] = {};

    for (int kt = 0; kt < EMB; kt += 64) {
        __syncthreads();
        const short* Ag = Xb + (size_t)bm*EMB + kt;
        const short* Bg = Wt + (size_t)bn*EMB + kt;
        #pragma unroll
        for (int c = 0; c < 4; ++c) {
            int seg = wave*4 + c;               // 16 segments x 8 rows
            int grow = seg*8 + srow;
            glds16(Ag + (size_t)grow*EMB + scolsw, &As[seg*8][0]);
            glds16(Bg + (size_t)grow*EMB + scolsw, &Bs[seg*8][0]);
        }
        __syncthreads();
        #pragma unroll
        for (int ks = 0; ks < 64; ks += 32) {
            bf16x8 af[4], bfr[4];
            #pragma unroll
            for (int mi=0;mi<4;++mi) af[mi]  = *(const bf16x8*)&As[wm + mi*16 + l16][(ks + quad*8) ^ rsw];
            #pragma unroll
            for (int ni=0;ni<4;++ni) bfr[ni] = *(const bf16x8*)&Bs[wn + ni*16 + l16][(ks + quad*8) ^ rsw];
            #pragma unroll
            for (int mi=0;mi<4;++mi)
                #pragma unroll
                for (int ni=0;ni<4;++ni)
                    acc[mi][ni] = __builtin_amdgcn_mfma_f32_16x16x32_bf16(af[mi], bfr[ni], acc[mi][ni], 0,0,0);
        }
    }

    #pragma unroll
    for (int ni=0;ni<4;++ni) {
        int c = bn + wn + ni*16 + l16;
        float bval = bias[c];
        int h = c >> 6, d = c & 63;
        #pragma unroll
        for (int mi=0;mi<4;++mi) {
            #pragma unroll
            for (int j=0;j<4;++j) {
                int r = bm + wm + mi*16 + quad*4 + j;
                int tt = r >> 1, bb = r & 1;
                float val = (acc[mi][ni][j] + bval) * scale;
                if (which == 2)
                    Vt[((size_t)(bb*NH+h)*HD + d)*T_LEN + tt] = f2bf(val);
                else {
                    short* dst = (which==0) ? Qb : Kb;
                    dst[((size_t)(bb*NH+h)*T_LEN + tt)*HD + d] = f2bf(val);
                }
            }
        }
    }
}

// ---------------- K2: MFMA flash attention, no-max exp2 softmax -----------
// 8 waves x 16 q = 128 q-rows (512 threads). Double-buffered K/V LDS with
// register prefetch (T14), single barrier per tile, P never touches LDS,
// KPAD=68 (0 bank conflicts measured). T1 XCD swizzle: each XCD owns 5
// consecutive bh x all 16 qt -> per-XCD K/V footprint 2.6 MB (L2-resident),
// was: every XCD streamed all 40 bh (FETCH 87 MB vs 31 MB unique).
__global__ __launch_bounds__(512) void k_pv(
    const short* __restrict__ Qb, const short* __restrict__ Kb, const short* __restrict__ Vt,
    const int* __restrict__ kpm,
    float* __restrict__ Linv,
    short* __restrict__ AttnMidb)   // [4096][1280] bf16, r = t*BSZ + b
{
    // bijective XCD swizzle (640 blocks, 640%8==0): XCD k gets lin%8==k,
    // remapped to 80 consecutive work ids = bh in [5k,5k+5) x 16 qt.
    int lin = blockIdx.y*gridDim.x + blockIdx.x;
    lin = (lin & 7) * 80 + (lin >> 3);
    const int qt = lin & 15;            // 16 tiles of 128 q
    const int bh = lin >> 4;
    const int b  = bh / NH, h = bh % NH;
    const int t    = threadIdx.x;
    const int w    = t >> 6;            // 0..7
    const int lane = t & 63;
    const int l16  = lane & 15;
    const int quad = lane >> 4;
    const int q0   = qt*128 + w*16;     // wave's first q-row

    __shared__ short Ks[2][64][KPAD];   // [buf][key][d]
    __shared__ short Vts[2][64][KPAD];  // [buf][d][key]
    __shared__ float MfL[2][64];        // mask floats, double-buffered
    __shared__ float Lsh[128];

    // Q fragments resident: used as MFMA *B* operand (n=q, k=d)
    bf16x8 qf[2];
    #pragma unroll
    for (int ch=0;ch<2;++ch)
        qf[ch] = *(const bf16x8*)(Qb + ((size_t)bh*T_LEN + q0 + l16)*HD + ch*32 + quad*8);

    const int row0 = t >> 3, col8 = (t & 7) * 8;    // 512 threads cover 64 rows
    const short* Kgb = Kb + (size_t)bh*T_LEN*HD;
    const short* Vgb = Vt + (size_t)bh*HD*T_LEN;

    // prologue: stage tile 0 directly
    *(bf16x8*)&Ks[0][row0][col8]  = *(const bf16x8*)(Kgb + (size_t)row0*HD + col8);
    *(bf16x8*)&Vts[0][row0][col8] = *(const bf16x8*)(Vgb + (size_t)row0*T_LEN + col8);
    if (t < 64) MfL[0][t] = kpm[b*T_LEN + t] ? 0.f : 1.f;
    __syncthreads();

    f32x4 o[4] = {};                    // [d-block], C-layout
    float l = 0.f;                      // per-quad partial row sum
    int cur = 0;

    for (int kt = 0; kt < T_LEN; kt += 64) {
        const int ktn = kt + 64;
        const bool has_next = ktn < T_LEN;
        const int nxt = cur ^ 1;

        // T14: issue next tile's global loads NOW; ds_write after QK^T+softmax
        bf16x8 kr0, vr0;
        float mfn = 0.f;
        if (has_next) {
            kr0 = *(const bf16x8*)(Kgb + (size_t)(ktn + row0)*HD + col8);
            vr0 = *(const bf16x8*)(Vgb + (size_t)row0*T_LEN + ktn + col8);
            if (t < 64) mfn = kpm[b*T_LEN + ktn + t] ? 0.f : 1.f;
        }

        // S^T[key][q]: lane holds q = l16 (col), key = mb*16+quad*4+r (row)
        f32x4 s[4] = {};
        #pragma unroll
        for (int ch = 0; ch < 2; ++ch) {
            bf16x8 ka[4];
            #pragma unroll
            for (int mb=0;mb<4;++mb) ka[mb] = *(const bf16x8*)&Ks[cur][mb*16 + l16][ch*32 + quad*8];
            #pragma unroll
            for (int mb=0;mb<4;++mb)
                s[mb] = __builtin_amdgcn_mfma_f32_16x16x32_bf16(ka[mb], qf[ch], s[mb], 0,0,0);
        }

        // softmax fully in-register: p = exp2(s)*mask, accumulate l,
        // pack straight into PV A-fragment words (permuted key order).
        unsigned pu[2][4];              // [chunk][4 dwords = 8 bf16]
        #pragma unroll
        for (int c = 0; c < 2; ++c) {
            #pragma unroll
            for (int mb2 = 0; mb2 < 2; ++mb2) {
                const int mb = c*2 + mb2;
                float4 mf = *(const float4*)&MfL[cur][mb*16 + quad*4];
                float p0 = __builtin_amdgcn_exp2f(s[mb][0]) * mf.x;
                float p1 = __builtin_amdgcn_exp2f(s[mb][1]) * mf.y;
                float p2 = __builtin_amdgcn_exp2f(s[mb][2]) * mf.z;
                float p3 = __builtin_amdgcn_exp2f(s[mb][3]) * mf.w;
                l += (p0 + p1) + (p2 + p3);
                pu[c][mb2*2+0] = cvt_pk_bf16(p0, p1);
                pu[c][mb2*2+1] = cvt_pk_bf16(p2, p3);
            }
        }

        // write staged next tile (compiler inserts the vmcnt wait here)
        if (has_next) {
            *(bf16x8*)&Ks[nxt][row0][col8]  = kr0;
            *(bf16x8*)&Vts[nxt][row0][col8] = vr0;
            if (t < 64) MfL[nxt][t] = mfn;
        }

        // PV: B-fragment rows follow the same permuted key order
        #pragma unroll
        for (int c = 0; c < 2; ++c) {
            bf16x8 vv[4];
            #pragma unroll
            for (int nb=0;nb<4;++nb) {
                bf16x4 va = *(const bf16x4*)&Vts[cur][nb*16 + l16][c*32 + quad*4];
                bf16x4 vb = *(const bf16x4*)&Vts[cur][nb*16 + l16][c*32 + 16 + quad*4];
                vv[nb] = (bf16x8){va[0],va[1],va[2],va[3], vb[0],vb[1],vb[2],vb[3]};
            }
            union { unsigned u[4]; bf16x8 v; } pa;
            pa.u[0]=pu[c][0]; pa.u[1]=pu[c][1];
            pa.u[2]=pu[c][2]; pa.u[3]=pu[c][3];
            #pragma unroll
            for (int nb=0;nb<4;++nb)
                o[nb] = __builtin_amdgcn_mfma_f32_16x16x32_bf16(pa.v, vv[nb], o[nb], 0,0,0);
        }

        __syncthreads();   // single barrier per tile: nxt fully written, cur free
        cur = nxt;
    }

    // finalize l: reduce across quads (only cross-lane op in the kernel)
    l += __shfl_xor(l, 16);
    l += __shfl_xor(l, 32);
    float linv = 1.0f / l;
    if (quad == 0) {
        Linv[(size_t)bh*T_LEN + q0 + l16] = linv;
        Lsh[w*16 + l16] = linv;
    }
    // per-wave region of Lsh; same-wave ds ordering suffices (no barrier)
    {
        float4 li = *(const float4*)&Lsh[w*16 + quad*4];
        float lr[4] = {li.x, li.y, li.z, li.w};
        #pragma unroll
        for (int r=0;r<4;++r) {
            int q = q0 + quad*4 + r;
            size_t base = ((size_t)q*BSZ + b)*EMB + h*HD;
            #pragma unroll
            for (int nb=0;nb<4;++nb)
                AttnMidb[base + nb*16 + l16] = f2bf(o[nb][r] * lr[r]);
        }
    }
}

// ---------------- K3: avg_weights via MFMA, 64q x 64k tile ----------------
// T14 restructure: double-buffered Q/K/Linv over the head loop, register
// prefetch of head h+1 during head h's compute, ONE barrier per head
// (was 2 barriers + serial stage->MFMA->exp2 chain). Same accumulation
// order -> bit-identical output. XCD swizzle on the flattened work id.
__global__ __launch_bounds__(256) void k_meanw(
    const short* __restrict__ Qb, const short* __restrict__ Kb,
    const int* __restrict__ kpm,
    const float* __restrict__ Linv,
    float* __restrict__ avg)   // [BSZ][T_LEN][T_LEN]
{
    int lin = (blockIdx.z*gridDim.y + blockIdx.y)*gridDim.x + blockIdx.x;
    lin = (lin & 7) * 256 + (lin >> 3);     // 2048%8==0: bijective
    const int kt = lin & 31;
    const int qt = (lin >> 5) & 31;
    const int b  = lin >> 10;

    const int t    = threadIdx.x;
    const int wave = t >> 6, lane = t & 63;
    const int l16  = lane & 15, quad = lane >> 4;

    __shared__ short Qs[2][64][KPAD];
    __shared__ short Ks[2][64][KPAD];
    __shared__ float Lish[2][64];
    __shared__ int   msk[64];

    const int srow = t >> 2;            // 0..63
    const int scol = (t & 3) * 16;      // 0,16,32,48

    const short* Qg0 = Qb + ((size_t)(b*NH)*T_LEN + qt*64)*HD;
    const short* Kg0 = Kb + ((size_t)(b*NH)*T_LEN + kt*64)*HD;
    const size_t hstride = (size_t)T_LEN*HD;

    if (t < 64) msk[t] = kpm[b*T_LEN + kt*64 + t];

    // prologue: stage head 0
    *(bf16x8*)&Qs[0][srow][scol]   = *(const bf16x8*)(Qg0 + (size_t)srow*HD + scol);
    *(bf16x8*)&Qs[0][srow][scol+8] = *(const bf16x8*)(Qg0 + (size_t)srow*HD + scol + 8);
    *(bf16x8*)&Ks[0][srow][scol]   = *(const bf16x8*)(Kg0 + (size_t)srow*HD + scol);
    *(bf16x8*)&Ks[0][srow][scol+8] = *(const bf16x8*)(Kg0 + (size_t)srow*HD + scol + 8);
    if (t < 64) Lish[0][t] = Linv[(size_t)(b*NH)*T_LEN + qt*64 + t];
    __syncthreads();

    f32x4 acc[4] = {};
    const int qrow_in = wave*16 + quad*4;   // + r
    int cur = 0;

    for (int h = 0; h < NH; ++h) {
        const int nxt = cur ^ 1;

        // prefetch head h+1 into registers (latency hides under compute)
        bf16x8 qr0, qr1, kr0, kr1;
        float lnx = 0.f;
        if (h+1 < NH) {
            const short* Qg = Qg0 + (size_t)(h+1)*hstride;
            const short* Kg = Kg0 + (size_t)(h+1)*hstride;
            qr0 = *(const bf16x8*)(Qg + (size_t)srow*HD + scol);
            qr1 = *(const bf16x8*)(Qg + (size_t)srow*HD + scol + 8);
            kr0 = *(const bf16x8*)(Kg + (size_t)srow*HD + scol);
            kr1 = *(const bf16x8*)(Kg + (size_t)srow*HD + scol + 8);
            if (t < 64) lnx = Linv[(size_t)(b*NH + h+1)*T_LEN + qt*64 + t];
        }

        bf16x8 aq0 = *(const bf16x8*)&Qs[cur][wave*16 + l16][quad*8];
        bf16x8 aq1 = *(const bf16x8*)&Qs[cur][wave*16 + l16][32 + quad*8];

        float lv[4];
        #pragma unroll
        for (int r = 0; r < 4; ++r)
            lv[r] = Lish[cur][qrow_in + r] * (1.0f/NH);

        #pragma unroll
        for (int nb = 0; nb < 4; ++nb) {
            bf16x8 bk0 = *(const bf16x8*)&Ks[cur][nb*16 + l16][quad*8];
            bf16x8 bk1 = *(const bf16x8*)&Ks[cur][nb*16 + l16][32 + quad*8];
            f32x4 s = {};
            s = __builtin_amdgcn_mfma_f32_16x16x32_bf16(aq0, bk0, s, 0,0,0);
            s = __builtin_amdgcn_mfma_f32_16x16x32_bf16(aq1, bk1, s, 0,0,0);
            const bool mk = msk[nb*16 + l16] != 0;
            #pragma unroll
            for (int r = 0; r < 4; ++r)
                acc[nb][r] += mk ? 0.f : __builtin_amdgcn_exp2f(s[r]) * lv[r];
        }

        // write staged next head (vmcnt wait lands here, after compute)
        if (h+1 < NH) {
            *(bf16x8*)&Qs[nxt][srow][scol]   = qr0;
            *(bf16x8*)&Qs[nxt][srow][scol+8] = qr1;
            *(bf16x8*)&Ks[nxt][srow][scol]   = kr0;
            *(bf16x8*)&Ks[nxt][srow][scol+8] = kr1;
            if (t < 64) Lish[nxt][t] = lnx;
        }
        __syncthreads();
        cur = nxt;
    }

    #pragma unroll
    for (int r = 0; r < 4; ++r) {
        int q = qt*64 + qrow_in + r;
        size_t base = ((size_t)b*T_LEN + q) * T_LEN + (size_t)kt*64;
        #pragma unroll
        for (int nb = 0; nb < 4; ++nb)
            avg[base + nb*16 + l16] = acc[nb][r];
    }
}

// ---------------- K4: output projection, bf16 MFMA 128x128xBK64 ------------
__global__ __launch_bounds__(256) void k_gemm_out(
    const short* __restrict__ Ab, const short* __restrict__ Wot,
    const float* __restrict__ bo, float* __restrict__ out)
{
    const int bm = blockIdx.y * 128;
    const int bn = blockIdx.x * 128;
    const int t    = threadIdx.x;
    const int wave = t >> 6, lane = t & 63;
    const int l16  = lane & 15, quad = lane >> 4;
    const int wm   = (wave >> 1) * 64, wn = (wave & 1) * 64;

    __shared__ short As[128][64];
    __shared__ short Bs[128][64];

    const int srow   = lane >> 3;
    const int scolsw = (((lane & 7) ^ srow) & 7) * 8;
    const int rsw    = (l16 & 7) << 3;

    f32x4 acc[4][4] = {};

    for (int kt = 0; kt < EMB; kt += 64) {
        __syncthreads();
        const short* Ag = Ab  + (size_t)bm*EMB + kt;
        const short* Bg = Wot + (size_t)bn*EMB + kt;
        #pragma unroll
        for (int c = 0; c < 4; ++c) {
            int seg = wave*4 + c;
            int grow = seg*8 + srow;
            glds16(Ag + (size_t)grow*EMB + scolsw, &As[seg*8][0]);
            glds16(Bg + (size_t)grow*EMB + scolsw, &Bs[seg*8][0]);
        }
        __syncthreads();
        #pragma unroll
        for (int ks = 0; ks < 64; ks += 32) {
            bf16x8 af[4], bfr[4];
            #pragma unroll
            for (int mi=0;mi<4;++mi) af[mi]  = *(const bf16x8*)&As[wm + mi*16 + l16][(ks + quad*8) ^ rsw];
            #pragma unroll
            for (int ni=0;ni<4;++ni) bfr[ni] = *(const bf16x8*)&Bs[wn + ni*16 + l16][(ks + quad*8) ^ rsw];
            #pragma unroll
            for (int mi=0;mi<4;++mi)
                #pragma unroll
                for (int ni=0;ni<4;++ni)
                    acc[mi][ni] = __builtin_amdgcn_mfma_f32_16x16x32_bf16(af[mi], bfr[ni], acc[mi][ni], 0,0,0);
        }
    }

    #pragma unroll
    for (int ni=0;ni<4;++ni) {
        int c = bn + wn + ni*16 + l16;
        float bval = bo[c];
        #pragma unroll
        for (int mi=0;mi<4;++mi) {
            #pragma unroll
            for (int j=0;j<4;++j) {
                int r = bm + wm + mi*16 + quad*4 + j;
                out[(size_t)r*EMB + c] = acc[mi][ni][j] + bval;
            }
        }
    }
}

extern "C" void kernel_launch(void* const* d_in, const int* in_sizes, int n_in,
                              void* d_out, int out_size, void* d_ws, size_t ws_size,
                              hipStream_t stream) {
    const float* X   = (const float*)d_in[0];
    const int*   kpm = (const int*)  d_in[1];
    const float* Wq  = (const float*)d_in[2];
    const float* bq  = (const float*)d_in[3];
    const float* Wk  = (const float*)d_in[4];
    const float* bk  = (const float*)d_in[5];
    const float* Wv  = (const float*)d_in[6];
    const float* bv  = (const float*)d_in[7];
    const float* Wo  = (const float*)d_in[8];
    const float* bo  = (const float*)d_in[9];

    float* out = (float*)d_out;
    float* ws  = (float*)d_ws;

    const size_t QKV = (size_t)NBH * T_LEN * HD;   // 5,242,880
    float* Linv = ws;
    short* Xb   = (short*)(Linv + (size_t)NBH * T_LEN);
    short* Wqt  = Xb  + (size_t)NR * EMB;
    short* Wkt  = Wqt + (size_t)EMB * EMB;
    short* Wvt  = Wkt + (size_t)EMB * EMB;
    short* Wot  = Wvt + (size_t)EMB * EMB;
    short* Qb   = Wot + (size_t)EMB * EMB;
    short* Kb   = Qb  + QKV;
    short* Vt   = Kb  + QKV;
    short* Amid = Vt  + QKV;

    float* attn_out = out;                              // [T_LEN, BSZ, EMB]
    float* avg      = out + (size_t)T_LEN * BSZ * EMB;  // [BSZ, T_LEN, T_LEN]

    k_cvt_x   <<<dim3((NR*EMB)/(256*8)), 256, 0, stream>>>(X, Xb);
    k_cvt_wt  <<<dim3(EMB/32, EMB/32, 4), 256, 0, stream>>>(Wq, Wk, Wv, Wo, Wqt, Wkt, Wvt, Wot);
    k_gemm_qkv<<<dim3(EMB/128, NR/128, 3), 256, 0, stream>>>(Xb, Wqt, Wkt, Wvt, bq, bk, bv, Qb, Kb, Vt);
    k_pv      <<<dim3(T_LEN/128, NBH),   512, 0, stream>>>(Qb, Kb, Vt, kpm, Linv, Amid);
    k_meanw   <<<dim3(T_LEN/64, T_LEN/64, BSZ), 256, 0, stream>>>(Qb, Kb, kpm, Linv, avg);
    k_gemm_out<<<dim3(EMB/128, NR/128),  256, 0, stream>>>(Amid, Wot, bo, attn_out);
}